// Round 8
// baseline (115.135 us; speedup 1.0000x reference)
//
#include <hip/hip_runtime.h>
#include <hip/hip_bf16.h>

#define T_SEQ 2048
#define BATCH 2
#define DMODEL 512
#define NHEAD 8
#define DHEAD 64
#define DVAL 64
#define BH 16
#define CHUNK 64
#define NCHUNK 32
#define MROWS 4096   // BATCH*T_SEQ

typedef __bf16 bf16;
typedef __bf16 bf16x8 __attribute__((ext_vector_type(8)));
typedef __bf16 bf16x4 __attribute__((ext_vector_type(4)));
typedef float f32x4 __attribute__((ext_vector_type(4)));

__device__ inline void gload_lds16(const bf16* g, bf16* l) {
  __builtin_amdgcn_global_load_lds((const __attribute__((address_space(1))) void*)g,
                                   (__attribute__((address_space(3))) void*)l, 16, 0, 0);
}

// XOR-swizzled slot offset (elements) for 64-col bf16 LDS tiles.
__device__ inline int sw_t(int row, int g) {
  return ((g ^ (row & 7) ^ (row >> 3)) << 3);
}

// ---------------- kernel 0: fp32 -> bf16 conversion (vectorized) ----------------
__global__ __launch_bounds__(256) void k_convert(const float* __restrict__ x,
                          const float* __restrict__ wq,
                          const float* __restrict__ wk,
                          const float* __restrict__ wv,
                          const float* __restrict__ wo,
                          bf16* __restrict__ x_bf,
                          bf16* __restrict__ wqkv_bf,
                          bf16* __restrict__ wo_bf) {
  const int W = DMODEL * DMODEL;           // 262144
  int i = blockIdx.x * 256 + threadIdx.x;  // 0..524287 (grid 2048)
  {
    f32x4 v = ((const f32x4*)x)[i];
    bf16x4 o; o[0] = (bf16)v[0]; o[1] = (bf16)v[1]; o[2] = (bf16)v[2]; o[3] = (bf16)v[3];
    *(bf16x4*)(x_bf + (size_t)i * 4) = o;
  }
  if (i < W / 4) {
    f32x4 a = ((const f32x4*)wq)[i];
    f32x4 b = ((const f32x4*)wk)[i];
    f32x4 c = ((const f32x4*)wv)[i];
    f32x4 d = ((const f32x4*)wo)[i];
    bf16x4 oa, ob, oc, od;
#pragma unroll
    for (int u = 0; u < 4; u++) { oa[u] = (bf16)a[u]; ob[u] = (bf16)b[u]; oc[u] = (bf16)c[u]; od[u] = (bf16)d[u]; }
    *(bf16x4*)(wqkv_bf + (size_t)i * 4) = oa;
    *(bf16x4*)(wqkv_bf + W + (size_t)i * 4) = ob;
    *(bf16x4*)(wqkv_bf + 2 * W + (size_t)i * 4) = oc;
    *(bf16x4*)(wo_bf + (size_t)i * 4) = od;
  }
}

// ---------------- QKV GEMM: 64x128 tile, BK=64, grid (64,12)=768=3/CU ----------------
__global__ __launch_bounds__(256) void k_gemm_qkv(const bf16* __restrict__ A,
                                                  const bf16* __restrict__ B,
                                                  bf16* __restrict__ Q,
                                                  bf16* __restrict__ K,
                                                  bf16* __restrict__ V) {
  __shared__ bf16 sh[12288];   // As(4096) + Bs(8192) = 24 KB; reused as repack scratch
  bf16* As = sh;
  bf16* Bs = sh + 4096;
  const int tid = threadIdx.x;
  const int wvi = tid >> 6, lane = tid & 63;
  const int c = lane & 15, quad = lane >> 4;
  const int m_tile = blockIdx.x * 64, n_tile = blockIdx.y * 128;
  const int r8 = lane >> 3, gp = lane & 7;
  const bf16* Abase = A + (size_t)m_tile * DMODEL;
  const bf16* Bbase = B + (size_t)n_tile * DMODEL;
  const int wn = wvi * 32;

  f32x4 acc[4][2] = {};

  for (int k0 = 0; k0 < DMODEL; k0 += 64) {
    if (k0) __syncthreads();
#pragma unroll
    for (int r = 0; r < 2; r++) {
      int t8 = wvi * 2 + r;
      const bf16* ga = Abase + (size_t)(t8 * 8 + r8) * DMODEL + k0 + ((gp ^ r8) << 3);
      gload_lds16(ga, As + t8 * 8 * 64);
    }
#pragma unroll
    for (int r = 0; r < 4; r++) {
      int t8 = wvi * 4 + r;
      const bf16* gb = Bbase + (size_t)(t8 * 8 + r8) * DMODEL + k0 + ((gp ^ r8) << 3);
      gload_lds16(gb, Bs + t8 * 8 * 64);
    }
    __syncthreads();
#pragma unroll
    for (int ks = 0; ks < 2; ks++) {
      bf16x8 af[4], bfr[2];
#pragma unroll
      for (int i = 0; i < 4; i++)
        af[i] = *(const bf16x8*)(As + (i * 16 + c) * 64 + (((ks * 4 + quad) ^ (c & 7)) << 3));
#pragma unroll
      for (int j = 0; j < 2; j++)
        bfr[j] = *(const bf16x8*)(Bs + (wn + j * 16 + c) * 64 + (((ks * 4 + quad) ^ (c & 7)) << 3));
#pragma unroll
      for (int i = 0; i < 4; i++)
#pragma unroll
        for (int j = 0; j < 2; j++)
          acc[i][j] = __builtin_amdgcn_mfma_f32_16x16x32_bf16(af[i], bfr[j], acc[i][j], 0, 0, 0);
    }
  }

  // bf16 repack: 64x128 tile, stride 132, then 4x b128 stores/thread
  const bool is_qk = (n_tile < 1024);   // uniform per block
  __syncthreads();
#pragma unroll
  for (int i = 0; i < 4; i++)
#pragma unroll
    for (int j = 0; j < 2; j++)
#pragma unroll
      for (int r = 0; r < 4; r++) {
        int row = i * 16 + quad * 4 + r;
        int col = wn + j * 16 + c;
        float v = acc[i][j][r];
        if (is_qk) v = (v > 0.f) ? (v + 1.f) : __expf(v);  // phi = elu+1
        sh[row * 132 + col] = (bf16)v;
      }
  __syncthreads();
  bf16* dst = (n_tile < 512) ? Q : ((n_tile < 1024) ? K : V);
  int nb = n_tile & 511;
#pragma unroll
  for (int q = 0; q < 4; q++) {
    int row = q * 16 + (tid >> 4);
    int col0 = (tid & 15) * 8;
    bf16x8 v8 = *(const bf16x8*)(sh + row * 132 + col0);
    *(bf16x8*)(dst + (size_t)(m_tile + row) * 512 + nb + col0) = v8;
  }
}

// ---------------- Out GEMM: 32x128 tile, BK=64, grid (128,4)=512=2/CU ----------------
__global__ __launch_bounds__(256) void k_gemm_out(const bf16* __restrict__ A,
                                                  const bf16* __restrict__ B,
                                                  float* __restrict__ out) {
  __shared__ bf16 sh[10240];   // As(2048) + Bs(8192) = 20 KB; repack 32x132 fp32 = 16.9 KB
  bf16* As = sh;
  bf16* Bs = sh + 2048;
  const int tid = threadIdx.x;
  const int wvi = tid >> 6, lane = tid & 63;
  const int c = lane & 15, quad = lane >> 4;
  const int m_tile = blockIdx.x * 32, n_tile = blockIdx.y * 128;
  const int r8 = lane >> 3, gp = lane & 7;
  const bf16* Abase = A + (size_t)m_tile * DMODEL;
  const bf16* Bbase = B + (size_t)n_tile * DMODEL;
  const int wn = wvi * 32;

  f32x4 acc[2][2] = {};

  for (int k0 = 0; k0 < DMODEL; k0 += 64) {
    if (k0) __syncthreads();
    {
      int t8 = wvi;                         // A: 32 rows = 4 groups of 8
      const bf16* ga = Abase + (size_t)(t8 * 8 + r8) * DMODEL + k0 + ((gp ^ r8) << 3);
      gload_lds16(ga, As + t8 * 8 * 64);
    }
#pragma unroll
    for (int r = 0; r < 4; r++) {           // B: 128 rows = 16 groups of 8
      int t8 = wvi * 4 + r;
      const bf16* gb = Bbase + (size_t)(t8 * 8 + r8) * DMODEL + k0 + ((gp ^ r8) << 3);
      gload_lds16(gb, Bs + t8 * 8 * 64);
    }
    __syncthreads();
#pragma unroll
    for (int ks = 0; ks < 2; ks++) {
      bf16x8 af[2], bfr[2];
#pragma unroll
      for (int i = 0; i < 2; i++)
        af[i] = *(const bf16x8*)(As + (i * 16 + c) * 64 + (((ks * 4 + quad) ^ (c & 7)) << 3));
#pragma unroll
      for (int j = 0; j < 2; j++)
        bfr[j] = *(const bf16x8*)(Bs + (wn + j * 16 + c) * 64 + (((ks * 4 + quad) ^ (c & 7)) << 3));
#pragma unroll
      for (int i = 0; i < 2; i++)
#pragma unroll
        for (int j = 0; j < 2; j++)
          acc[i][j] = __builtin_amdgcn_mfma_f32_16x16x32_bf16(af[i], bfr[j], acc[i][j], 0, 0, 0);
    }
  }

  // fp32 repack (32x132 floats) + 4x dwordx4 stores per thread
  float* shf = (float*)sh;
  __syncthreads();
#pragma unroll
  for (int i = 0; i < 2; i++)
#pragma unroll
    for (int j = 0; j < 2; j++)
#pragma unroll
      for (int r = 0; r < 4; r++)
        shf[(i * 16 + quad * 4 + r) * 132 + wn + j * 16 + c] = acc[i][j][r];
  __syncthreads();
  int row = tid >> 3, col0 = (tid & 7) * 16;
#pragma unroll
  for (int q4 = 0; q4 < 4; q4++) {
    f32x4 v4 = *(const f32x4*)(shf + row * 132 + col0 + q4 * 4);
    *(f32x4*)(out + (size_t)(m_tile + row) * 512 + n_tile + col0 + q4 * 4) = v4;
  }
}

// ---------------- kernel 2: per-chunk S^T_c = V^T K (MFMA) + z_c ----------------
// State stored in register-layout slot order (slot s=f*4+r at op+tid*16+s).
__global__ __launch_bounds__(256) void k_state(const bf16* __restrict__ K,
                                               const bf16* __restrict__ V,
                                               bf16* __restrict__ KVs,
                                               float* __restrict__ zsum) {
  __shared__ bf16 Kt[4096];   // Kt[i][t] swizzled
  __shared__ bf16 Vt[4096];   // Vt[j][t] swizzled
  int chunk = blockIdx.x, bh = blockIdx.y;
  int b = bh >> 3, h = bh & 7;
  int tid = threadIdx.x, lane = tid & 63, wvi = tid >> 6;
  int rowbase = b * T_SEQ + chunk * CHUNK;

#pragma unroll
  for (int p = 0; p < 2; p++) {
    int r = p * 32 + (tid >> 3);
    int j0 = (tid & 7) * 8;
    bf16x8 kk  = *(const bf16x8*)(K + (size_t)(rowbase + r) * 512 + h * 64 + j0);
    bf16x8 vvv = *(const bf16x8*)(V + (size_t)(rowbase + r) * 512 + h * 64 + j0);
#pragma unroll
    for (int u = 0; u < 8; u++) {
      int row = j0 + u;
      Kt[row * 64 + sw_t(row, r >> 3) + (r & 7)] = kk[u];
      Vt[row * 64 + sw_t(row, r >> 3) + (r & 7)] = vvv[u];
    }
  }
  __syncthreads();

  int c = lane & 15, quad = lane >> 4;
  f32x4 acc[4] = {};
#pragma unroll
  for (int ks = 0; ks < 2; ks++) {
    int ar = wvi * 16 + c;
    bf16x8 a = *(const bf16x8*)(Vt + ar * 64 + sw_t(ar, ks * 4 + quad));
#pragma unroll
    for (int f = 0; f < 4; f++) {
      int br = f * 16 + c;
      bf16x8 bb = *(const bf16x8*)(Kt + br * 64 + sw_t(br, ks * 4 + quad));
      acc[f] = __builtin_amdgcn_mfma_f32_16x16x32_bf16(a, bb, acc[f], 0, 0, 0);
    }
  }
  bf16* op = KVs + ((size_t)(bh * NCHUNK + chunk) << 12);
  bf16x8 lo, hi;
#pragma unroll
  for (int u = 0; u < 8; u++) {
    lo[u] = (bf16)acc[u >> 2][u & 3];
    hi[u] = (bf16)acc[2 + (u >> 2)][u & 3];
  }
  *(bf16x8*)(op + tid * 16) = lo;
  *(bf16x8*)(op + tid * 16 + 8) = hi;

  if (tid < 64) {
    float s = 0.f;
#pragma unroll
    for (int g = 0; g < 8; g++) {
      bf16x8 kr = *(const bf16x8*)(Kt + tid * 64 + sw_t(tid, g));
#pragma unroll
      for (int u = 0; u < 8; u++) s += (float)kr[u];
    }
    zsum[(size_t)(bh * NCHUNK + chunk) * 64 + tid] = s;
  }
}

// ---------------- kernel 3: prefix + intra-chunk attention, 2 chunks per block ----------------
__global__ __launch_bounds__(256) void k_attn(const bf16* __restrict__ Q,
                                              const bf16* __restrict__ K,
                                              const bf16* __restrict__ V,
                                              const bf16* __restrict__ KVs,
                                              const float* __restrict__ zsum,
                                              bf16* __restrict__ O) {
  __shared__ bf16 SH[20480];
  bf16* Qs   = SH;            // 4096, async-staged row layout
  bf16* Ks   = SH + 4096;     // 4096
  bf16* Vt   = SH + 8192;     // 4096, transposed sw_t
  bf16* Asm  = SH + 12288;    // 4096, attention matrix
  bf16* Spre = SH + 16384;    // 4096, S^T_prefix
  __shared__ float zp4[4][64];
  __shared__ float zpre[64], rsum[64], den[64];

  int cp = blockIdx.x, bh = blockIdx.y;      // chunk pair cp -> chunks 2cp, 2cp+1
  int b = bh >> 3, h = bh & 7;
  int tid = threadIdx.x, lane = tid & 63, wvi = tid >> 6;
  int c = lane & 15, quad = lane >> 4;
  const int r8 = lane >> 3, gp = lane & 7;

  float accp[16];   // running S^T prefix, register-resident across both chunks
#pragma unroll
  for (int u = 0; u < 16; u++) accp[u] = 0.f;

  for (int ch = 0; ch < 2; ch++) {
    int chunk = cp * 2 + ch;
    int rowbase = b * T_SEQ + chunk * CHUNK;

    if (ch == 1) __syncthreads();   // B5: chunk0 repack-store reads complete

    // async stage Qs, Ks for this chunk
#pragma unroll
    for (int p = 0; p < 2; p++) {
      int rbase = p * 32 + wvi * 8;
      const bf16* gq = Q + (size_t)(rowbase + rbase + r8) * 512 + h * 64 + ((gp ^ r8) << 3);
      const bf16* gk = K + (size_t)(rowbase + rbase + r8) * 512 + h * 64 + ((gp ^ r8) << 3);
      gload_lds16(gq, Qs + rbase * 64);
      gload_lds16(gk, Ks + rbase * 64);
    }
    // V load + transpose into Vt
#pragma unroll
    for (int p = 0; p < 2; p++) {
      int r = p * 32 + (tid >> 3);
      int j0 = (tid & 7) * 8;
      bf16x8 vvv = *(const bf16x8*)(V + (size_t)(rowbase + r) * 512 + h * 64 + j0);
#pragma unroll
      for (int u = 0; u < 8; u++) {
        int row = j0 + u;
        Vt[row * 64 + sw_t(row, r >> 3) + (r & 7)] = vvv[u];
      }
    }

    if (ch == 0) {
      // prefix over cc < chunk (register accumulate)
      const bf16* base = KVs + ((size_t)(bh * NCHUNK) << 12) + tid * 16;
      for (int cc = 0; cc < chunk; cc++) {
        const bf16* pp = base + ((size_t)cc << 12);
        bf16x8 a0 = *(const bf16x8*)pp;
        bf16x8 a1 = *(const bf16x8*)(pp + 8);
#pragma unroll
        for (int u = 0; u < 8; u++) { accp[u] += (float)a0[u]; accp[8 + u] += (float)a1[u]; }
      }
      // z prefix partials (per wave)
      {
        int i = tid & 63, qq = tid >> 6;
        float s = 0.f;
        for (int cc = qq; cc < chunk; cc += 4)
          s += zsum[(size_t)(bh * NCHUNK + cc) * 64 + i];
        zp4[qq][i] = s;
      }
    } else {
      // prefix += state(chunk-1); zpre += zsum(chunk-1)
      const bf16* pp = KVs + ((size_t)(bh * NCHUNK + chunk - 1) << 12) + tid * 16;
      bf16x8 a0 = *(const bf16x8*)pp;
      bf16x8 a1 = *(const bf16x8*)(pp + 8);
#pragma unroll
      for (int u = 0; u < 8; u++) { accp[u] += (float)a0[u]; accp[8 + u] += (float)a1[u]; }
      if (tid < 64) zpre[tid] += zsum[(size_t)(bh * NCHUNK + chunk - 1) * 64 + tid];
    }
    // write Spre from registers (slot s -> rowV = wvi*16+quad*4+(s&3), colK = (s>>2)*16+c)
#pragma unroll
    for (int s = 0; s < 16; s++) {
      int rowp = wvi * 16 + quad * 4 + (s & 3);
      int colp = (s >> 2) * 16 + c;
      Spre[rowp * 64 + sw_t(rowp, colp >> 3) + (colp & 7)] = (bf16)accp[s];
    }
    __syncthreads();  // B1: all LDS staged (+ async loads drained)
    if (ch == 0 && tid < 64) zpre[tid] = zp4[0][tid] + zp4[1][tid] + zp4[2][tid] + zp4[3][tid];

    // QK^T
    f32x4 sacc[4] = {};
#pragma unroll
    for (int ks = 0; ks < 2; ks++) {
      int ar = 16 * wvi + c;
      bf16x8 a = *(const bf16x8*)(Qs + ar * 64 + (((ks * 4 + quad) ^ (c & 7)) << 3));
#pragma unroll
      for (int j = 0; j < 4; j++) {
        int br = 16 * j + c;
        bf16x8 bb = *(const bf16x8*)(Ks + br * 64 + (((ks * 4 + quad) ^ (c & 7)) << 3));
        sacc[j] = __builtin_amdgcn_mfma_f32_16x16x32_bf16(a, bb, sacc[j], 0, 0, 0);
      }
    }

    // mask, rowsum, write Asm
    float rs[4] = {0.f, 0.f, 0.f, 0.f};
#pragma unroll
    for (int j = 0; j < 4; j++) {
#pragma unroll
      for (int r = 0; r < 4; r++) {
        int t = 16 * wvi + quad * 4 + r, s = 16 * j + c;
        float v = (s <= t) ? sacc[j][r] : 0.f;
        rs[r] += v;
        Asm[t * 64 + sw_t(t, s >> 3) + (s & 7)] = (bf16)v;
      }
    }
#pragma unroll
    for (int r = 0; r < 4; r++) {
      float v = rs[r];
      v += __shfl_xor(v, 1); v += __shfl_xor(v, 2);
      v += __shfl_xor(v, 4); v += __shfl_xor(v, 8);
      if (c == 0) rsum[16 * wvi + quad * 4 + r] = v;
    }
    __syncthreads();  // B2: Asm, rsum, zpre visible

    // den[t] = max(rowsum + Q[t].z_pre, 1e-6)
    if (tid < 64) {
      float s = rsum[tid];
      int t7 = tid & 7;
#pragma unroll
      for (int kg = 0; kg < 8; kg++) {
        bf16x8 qv = *(const bf16x8*)(Qs + tid * 64 + ((kg ^ t7) << 3));
#pragma unroll
        for (int u = 0; u < 8; u++) s += (float)qv[u] * zpre[kg * 8 + u];
      }
      den[tid] = fmaxf(s, 1e-6f);
    }

    // O = Q.S_pre + A.V
    f32x4 oacc[4] = {};
#pragma unroll
    for (int ks = 0; ks < 2; ks++) {
      int ar = 16 * wvi + c;
      bf16x8 aq = *(const bf16x8*)(Qs + ar * 64 + (((ks * 4 + quad) ^ (c & 7)) << 3));
      bf16x8 aa = *(const bf16x8*)(Asm + ar * 64 + sw_t(ar, ks * 4 + quad));
#pragma unroll
      for (int j = 0; j < 4; j++) {
        int br = 16 * j + c;
        bf16x8 bs = *(const bf16x8*)(Spre + br * 64 + sw_t(br, ks * 4 + quad));
        bf16x8 bv = *(const bf16x8*)(Vt + br * 64 + sw_t(br, ks * 4 + quad));
        oacc[j] = __builtin_amdgcn_mfma_f32_16x16x32_bf16(aq, bs, oacc[j], 0, 0, 0);
        oacc[j] = __builtin_amdgcn_mfma_f32_16x16x32_bf16(aa, bv, oacc[j], 0, 0, 0);
      }
    }
    __syncthreads();  // B3: den visible; Qs/Ks region dead -> repack scratch

    // O repack (stride 76, overlays Qs/Ks) + vector store
    {
      bf16* shr = SH;
#pragma unroll
      for (int r = 0; r < 4; r++) {
        int t = 16 * wvi + quad * 4 + r;
        float rd = 1.f / den[t];
#pragma unroll
        for (int j = 0; j < 4; j++)
          shr[t * 76 + 16 * j + c] = (bf16)(oacc[j][r] * rd);
      }
      __syncthreads();  // B4
      int row = tid >> 2, col0 = (tid & 3) * 16;
      bf16x8 v0 = *(const bf16x8*)(shr + row * 76 + col0);
      bf16x8 v1 = *(const bf16x8*)(shr + row * 76 + col0 + 8);
      bf16* od = O + (size_t)(rowbase + row) * 512 + h * 64 + col0;
      *(bf16x8*)od = v0;
      *(bf16x8*)(od + 8) = v1;
    }
  }
}

extern "C" void kernel_launch(void* const* d_in, const int* in_sizes, int n_in,
                              void* d_out, int out_size, void* d_ws, size_t ws_size,
                              hipStream_t stream) {
  const float* x  = (const float*)d_in[0];
  const float* wq = (const float*)d_in[1];
  const float* wk = (const float*)d_in[2];
  const float* wv = (const float*)d_in[3];
  const float* wo = (const float*)d_in[4];
  float* out = (float*)d_out;

  char* p = (char*)d_ws;
  bf16* x_bf   = (bf16*)p; p += (size_t)MROWS * DMODEL * 2;
  bf16* wqkv_b = (bf16*)p; p += (size_t)3 * DMODEL * DMODEL * 2;
  bf16* wo_b   = (bf16*)p; p += (size_t)DMODEL * DMODEL * 2;
  bf16* Qb     = (bf16*)p; p += (size_t)MROWS * 512 * 2;
  bf16* Kb     = (bf16*)p; p += (size_t)MROWS * 512 * 2;
  bf16* Vb     = (bf16*)p; p += (size_t)MROWS * 512 * 2;
  bf16* Ob     = (bf16*)p; p += (size_t)MROWS * 512 * 2;
  bf16* KVs    = (bf16*)p; p += (size_t)BH * NCHUNK * DHEAD * DVAL * 2;
  float* zs    = (float*)p; p += (size_t)BH * NCHUNK * DHEAD * 4;

  k_convert<<<2048, 256, 0, stream>>>(x, wq, wk, wv, wo, x_bf, wqkv_b, wo_b);
  k_gemm_qkv<<<dim3(MROWS / 64, (3 * DMODEL) / 128), 256, 0, stream>>>(
      x_bf, wqkv_b, Qb, Kb, Vb);
  k_state<<<dim3(NCHUNK, BH), 256, 0, stream>>>(Kb, Vb, KVs, zs);
  k_attn<<<dim3(NCHUNK / 2, BH), 256, 0, stream>>>(Qb, Kb, Vb, KVs, zs, Ob);
  k_gemm_out<<<dim3(MROWS / 32, DMODEL / 128), 256, 0, stream>>>(Ob, wo_b, out);
}

// Round 9
// 111.203 us; speedup vs baseline: 1.0354x; 1.0354x over previous
//
#include <hip/hip_runtime.h>
#include <hip/hip_bf16.h>

#define T_SEQ 2048
#define BATCH 2
#define DMODEL 512
#define NHEAD 8
#define DHEAD 64
#define DVAL 64
#define BH 16
#define CHUNK 64
#define NCHUNK 32
#define MROWS 4096   // BATCH*T_SEQ

typedef __bf16 bf16;
typedef __bf16 bf16x8 __attribute__((ext_vector_type(8)));
typedef __bf16 bf16x4 __attribute__((ext_vector_type(4)));
typedef float f32x4 __attribute__((ext_vector_type(4)));

__device__ inline void gload_lds16(const bf16* g, bf16* l) {
  __builtin_amdgcn_global_load_lds((const __attribute__((address_space(1))) void*)g,
                                   (__attribute__((address_space(3))) void*)l, 16, 0, 0);
}

// XOR-swizzled slot offset (elements) for 64-col bf16 LDS tiles.
__device__ inline int sw_t(int row, int g) {
  return ((g ^ (row & 7) ^ (row >> 3)) << 3);
}

// ---------------- kernel 0: fp32 -> bf16 conversion (vectorized) ----------------
__global__ __launch_bounds__(256) void k_convert(const float* __restrict__ x,
                          const float* __restrict__ wq,
                          const float* __restrict__ wk,
                          const float* __restrict__ wv,
                          const float* __restrict__ wo,
                          bf16* __restrict__ x_bf,
                          bf16* __restrict__ wqkv_bf,
                          bf16* __restrict__ wo_bf) {
  const int W = DMODEL * DMODEL;           // 262144
  int i = blockIdx.x * 256 + threadIdx.x;  // 0..524287 (grid 2048)
  {
    f32x4 v = ((const f32x4*)x)[i];
    bf16x4 o; o[0] = (bf16)v[0]; o[1] = (bf16)v[1]; o[2] = (bf16)v[2]; o[3] = (bf16)v[3];
    *(bf16x4*)(x_bf + (size_t)i * 4) = o;
  }
  if (i < W / 4) {
    f32x4 a = ((const f32x4*)wq)[i];
    f32x4 b = ((const f32x4*)wk)[i];
    f32x4 c = ((const f32x4*)wv)[i];
    f32x4 d = ((const f32x4*)wo)[i];
    bf16x4 oa, ob, oc, od;
#pragma unroll
    for (int u = 0; u < 4; u++) { oa[u] = (bf16)a[u]; ob[u] = (bf16)b[u]; oc[u] = (bf16)c[u]; od[u] = (bf16)d[u]; }
    *(bf16x4*)(wqkv_bf + (size_t)i * 4) = oa;
    *(bf16x4*)(wqkv_bf + W + (size_t)i * 4) = ob;
    *(bf16x4*)(wqkv_bf + 2 * W + (size_t)i * 4) = oc;
    *(bf16x4*)(wo_bf + (size_t)i * 4) = od;
  }
}

// ---------------- QKV GEMM: 64x128 tile, BK=64, grid (64,12)=768=3/CU ----------------
__global__ __launch_bounds__(256) void k_gemm_qkv(const bf16* __restrict__ A,
                                                  const bf16* __restrict__ B,
                                                  bf16* __restrict__ Q,
                                                  bf16* __restrict__ K,
                                                  bf16* __restrict__ V) {
  __shared__ bf16 sh[12288];   // As(4096) + Bs(8192) = 24 KB; reused as repack scratch
  bf16* As = sh;
  bf16* Bs = sh + 4096;
  const int tid = threadIdx.x;
  const int wvi = tid >> 6, lane = tid & 63;
  const int c = lane & 15, quad = lane >> 4;
  const int m_tile = blockIdx.x * 64, n_tile = blockIdx.y * 128;
  const int r8 = lane >> 3, gp = lane & 7;
  const bf16* Abase = A + (size_t)m_tile * DMODEL;
  const bf16* Bbase = B + (size_t)n_tile * DMODEL;
  const int wn = wvi * 32;

  f32x4 acc[4][2] = {};

  for (int k0 = 0; k0 < DMODEL; k0 += 64) {
    if (k0) __syncthreads();
#pragma unroll
    for (int r = 0; r < 2; r++) {
      int t8 = wvi * 2 + r;
      const bf16* ga = Abase + (size_t)(t8 * 8 + r8) * DMODEL + k0 + ((gp ^ r8) << 3);
      gload_lds16(ga, As + t8 * 8 * 64);
    }
#pragma unroll
    for (int r = 0; r < 4; r++) {
      int t8 = wvi * 4 + r;
      const bf16* gb = Bbase + (size_t)(t8 * 8 + r8) * DMODEL + k0 + ((gp ^ r8) << 3);
      gload_lds16(gb, Bs + t8 * 8 * 64);
    }
    __syncthreads();
#pragma unroll
    for (int ks = 0; ks < 2; ks++) {
      bf16x8 af[4], bfr[2];
#pragma unroll
      for (int i = 0; i < 4; i++)
        af[i] = *(const bf16x8*)(As + (i * 16 + c) * 64 + (((ks * 4 + quad) ^ (c & 7)) << 3));
#pragma unroll
      for (int j = 0; j < 2; j++)
        bfr[j] = *(const bf16x8*)(Bs + (wn + j * 16 + c) * 64 + (((ks * 4 + quad) ^ (c & 7)) << 3));
#pragma unroll
      for (int i = 0; i < 4; i++)
#pragma unroll
        for (int j = 0; j < 2; j++)
          acc[i][j] = __builtin_amdgcn_mfma_f32_16x16x32_bf16(af[i], bfr[j], acc[i][j], 0, 0, 0);
    }
  }

  // bf16 repack: 64x128 tile, stride 132, then 4x b128 stores/thread
  const bool is_qk = (n_tile < 1024);   // uniform per block
  __syncthreads();
#pragma unroll
  for (int i = 0; i < 4; i++)
#pragma unroll
    for (int j = 0; j < 2; j++)
#pragma unroll
      for (int r = 0; r < 4; r++) {
        int row = i * 16 + quad * 4 + r;
        int col = wn + j * 16 + c;
        float v = acc[i][j][r];
        if (is_qk) v = (v > 0.f) ? (v + 1.f) : __expf(v);  // phi = elu+1
        sh[row * 132 + col] = (bf16)v;
      }
  __syncthreads();
  bf16* dst = (n_tile < 512) ? Q : ((n_tile < 1024) ? K : V);
  int nb = n_tile & 511;
#pragma unroll
  for (int q = 0; q < 4; q++) {
    int row = q * 16 + (tid >> 4);
    int col0 = (tid & 15) * 8;
    bf16x8 v8 = *(const bf16x8*)(sh + row * 132 + col0);
    *(bf16x8*)(dst + (size_t)(m_tile + row) * 512 + nb + col0) = v8;
  }
}

// ---------------- Out GEMM: 64x64 tile, BK=64, grid (64,8)=512=2/CU ----------------
__global__ __launch_bounds__(256) void k_gemm_out(const bf16* __restrict__ A,
                                                  const bf16* __restrict__ B,
                                                  float* __restrict__ out) {
  __shared__ bf16 sh[8192];    // As(4096) + Bs(4096) = 16 KB; repack 32x68 fp32 = 8.7 KB
  bf16* As = sh;
  bf16* Bs = sh + 4096;
  const int tid = threadIdx.x;
  const int wvi = tid >> 6, lane = tid & 63;
  const int c = lane & 15, quad = lane >> 4;
  const int m_tile = blockIdx.x * 64, n_tile = blockIdx.y * 64;
  const int r8 = lane >> 3, gp = lane & 7;
  const bf16* Abase = A + (size_t)m_tile * DMODEL;
  const bf16* Bbase = B + (size_t)n_tile * DMODEL;
  const int wn = wvi * 16;

  f32x4 acc[4] = {};

  for (int k0 = 0; k0 < DMODEL; k0 += 64) {
    if (k0) __syncthreads();
#pragma unroll
    for (int r = 0; r < 2; r++) {           // A: 64 rows = 8 groups of 8
      int t8 = wvi * 2 + r;
      const bf16* ga = Abase + (size_t)(t8 * 8 + r8) * DMODEL + k0 + ((gp ^ r8) << 3);
      gload_lds16(ga, As + t8 * 8 * 64);
    }
#pragma unroll
    for (int r = 0; r < 2; r++) {           // B: 64 rows = 8 groups of 8
      int t8 = wvi * 2 + r;
      const bf16* gb = Bbase + (size_t)(t8 * 8 + r8) * DMODEL + k0 + ((gp ^ r8) << 3);
      gload_lds16(gb, Bs + t8 * 8 * 64);
    }
    __syncthreads();
#pragma unroll
    for (int ks = 0; ks < 2; ks++) {
      bf16x8 af[4], bfr;
#pragma unroll
      for (int i = 0; i < 4; i++)
        af[i] = *(const bf16x8*)(As + (i * 16 + c) * 64 + (((ks * 4 + quad) ^ (c & 7)) << 3));
      bfr = *(const bf16x8*)(Bs + (wn + c) * 64 + (((ks * 4 + quad) ^ (c & 7)) << 3));
#pragma unroll
      for (int i = 0; i < 4; i++)
        acc[i] = __builtin_amdgcn_mfma_f32_16x16x32_bf16(af[i], bfr, acc[i], 0, 0, 0);
    }
  }

  // fp32 repack in two 32-row half passes (stride 68 floats, 8.7 KB)
  float* shf = (float*)sh;
#pragma unroll
  for (int p = 0; p < 2; p++) {
    __syncthreads();
#pragma unroll
    for (int i2 = 0; i2 < 2; i2++) {         // i-frags 2p, 2p+1
      int i = 2 * p + i2;
#pragma unroll
      for (int r = 0; r < 4; r++)
        shf[(i2 * 16 + quad * 4 + r) * 68 + wn + c] = acc[i][r];
    }
    __syncthreads();
    int row = tid >> 3, col0 = (tid & 7) * 8;
#pragma unroll
    for (int q4 = 0; q4 < 2; q4++) {
      f32x4 v4 = *(const f32x4*)(shf + row * 68 + col0 + q4 * 4);
      *(f32x4*)(out + (size_t)(m_tile + p * 32 + row) * 512 + n_tile + col0 + q4 * 4) = v4;
    }
  }
}

// ---------------- kernel 2: per-chunk S^T_c = V^T K (MFMA) + z_c ----------------
// State stored in register-layout slot order (slot s=f*4+r at op+tid*16+s).
__global__ __launch_bounds__(256) void k_state(const bf16* __restrict__ K,
                                               const bf16* __restrict__ V,
                                               bf16* __restrict__ KVs,
                                               float* __restrict__ zsum) {
  __shared__ bf16 Kt[4096];   // Kt[i][t] swizzled
  __shared__ bf16 Vt[4096];   // Vt[j][t] swizzled
  int chunk = blockIdx.x, bh = blockIdx.y;
  int b = bh >> 3, h = bh & 7;
  int tid = threadIdx.x, lane = tid & 63, wvi = tid >> 6;
  int rowbase = b * T_SEQ + chunk * CHUNK;

#pragma unroll
  for (int p = 0; p < 2; p++) {
    int r = p * 32 + (tid >> 3);
    int j0 = (tid & 7) * 8;
    bf16x8 kk  = *(const bf16x8*)(K + (size_t)(rowbase + r) * 512 + h * 64 + j0);
    bf16x8 vvv = *(const bf16x8*)(V + (size_t)(rowbase + r) * 512 + h * 64 + j0);
#pragma unroll
    for (int u = 0; u < 8; u++) {
      int row = j0 + u;
      Kt[row * 64 + sw_t(row, r >> 3) + (r & 7)] = kk[u];
      Vt[row * 64 + sw_t(row, r >> 3) + (r & 7)] = vvv[u];
    }
  }
  __syncthreads();

  int c = lane & 15, quad = lane >> 4;
  f32x4 acc[4] = {};
#pragma unroll
  for (int ks = 0; ks < 2; ks++) {
    int ar = wvi * 16 + c;
    bf16x8 a = *(const bf16x8*)(Vt + ar * 64 + sw_t(ar, ks * 4 + quad));
#pragma unroll
    for (int f = 0; f < 4; f++) {
      int br = f * 16 + c;
      bf16x8 bb = *(const bf16x8*)(Kt + br * 64 + sw_t(br, ks * 4 + quad));
      acc[f] = __builtin_amdgcn_mfma_f32_16x16x32_bf16(a, bb, acc[f], 0, 0, 0);
    }
  }
  bf16* op = KVs + ((size_t)(bh * NCHUNK + chunk) << 12);
  bf16x8 lo, hi;
#pragma unroll
  for (int u = 0; u < 8; u++) {
    lo[u] = (bf16)acc[u >> 2][u & 3];
    hi[u] = (bf16)acc[2 + (u >> 2)][u & 3];
  }
  *(bf16x8*)(op + tid * 16) = lo;
  *(bf16x8*)(op + tid * 16 + 8) = hi;

  if (tid < 64) {
    float s = 0.f;
#pragma unroll
    for (int g = 0; g < 8; g++) {
      bf16x8 kr = *(const bf16x8*)(Kt + tid * 64 + sw_t(tid, g));
#pragma unroll
      for (int u = 0; u < 8; u++) s += (float)kr[u];
    }
    zsum[(size_t)(bh * NCHUNK + chunk) * 64 + tid] = s;
  }
}

// ---------------- kernel 3: fused prefix + intra-chunk attention (MFMA) ----------------
__global__ __launch_bounds__(256) void k_attn(const bf16* __restrict__ Q,
                                              const bf16* __restrict__ K,
                                              const bf16* __restrict__ V,
                                              const bf16* __restrict__ KVs,
                                              const float* __restrict__ zsum,
                                              bf16* __restrict__ O) {
  __shared__ bf16 SH[20480];
  bf16* Qs   = SH;            // 4096, async-staged row layout
  bf16* Ks   = SH + 4096;     // 4096
  bf16* Vt   = SH + 8192;     // 4096, transposed sw_t
  bf16* Asm  = SH + 12288;    // 4096, attention matrix
  bf16* Spre = SH + 16384;    // 4096, S^T_prefix
  __shared__ float zp4[4][64];
  __shared__ float zpre[64], rsum[64], den[64];

  int chunk = blockIdx.x, bh = blockIdx.y;
  int b = bh >> 3, h = bh & 7;
  int tid = threadIdx.x, lane = tid & 63, wvi = tid >> 6;
  int c = lane & 15, quad = lane >> 4;
  int rowbase = b * T_SEQ + chunk * CHUNK;

  // async stage Qs, Ks
#pragma unroll
  for (int p = 0; p < 2; p++) {
    int rbase = p * 32 + wvi * 8;
    int r8 = lane >> 3, gp = lane & 7;
    const bf16* gq = Q + (size_t)(rowbase + rbase + r8) * 512 + h * 64 + ((gp ^ r8) << 3);
    const bf16* gk = K + (size_t)(rowbase + rbase + r8) * 512 + h * 64 + ((gp ^ r8) << 3);
    gload_lds16(gq, Qs + rbase * 64);
    gload_lds16(gk, Ks + rbase * 64);
  }

  // V load + transpose into Vt
#pragma unroll
  for (int p = 0; p < 2; p++) {
    int r = p * 32 + (tid >> 3);
    int j0 = (tid & 7) * 8;
    bf16x8 vvv = *(const bf16x8*)(V + (size_t)(rowbase + r) * 512 + h * 64 + j0);
#pragma unroll
    for (int u = 0; u < 8; u++) {
      int row = j0 + u;
      Vt[row * 64 + sw_t(row, r >> 3) + (r & 7)] = vvv[u];
    }
  }

  // prefix of chunk states (register-layout slots: s = f*4+r), fp32 accumulate
  {
    float accp[16];
#pragma unroll
    for (int u = 0; u < 16; u++) accp[u] = 0.f;
    const bf16* base = KVs + ((size_t)(bh * NCHUNK) << 12) + tid * 16;
    for (int cc = 0; cc < chunk; cc++) {
      const bf16* pp = base + ((size_t)cc << 12);
      bf16x8 a0 = *(const bf16x8*)pp;
      bf16x8 a1 = *(const bf16x8*)(pp + 8);
#pragma unroll
      for (int u = 0; u < 8; u++) { accp[u] += (float)a0[u]; accp[8 + u] += (float)a1[u]; }
    }
    // slot s -> (rowV = wvi*16+quad*4+(s&3), colK = (s>>2)*16 + c)
#pragma unroll
    for (int s = 0; s < 16; s++) {
      int rowp = wvi * 16 + quad * 4 + (s & 3);
      int colp = (s >> 2) * 16 + c;
      Spre[rowp * 64 + sw_t(rowp, colp >> 3) + (colp & 7)] = (bf16)accp[s];
    }
  }
  // z prefix partials (per wave)
  {
    int i = tid & 63, qq = tid >> 6;
    float s = 0.f;
    for (int cc = qq; cc < chunk; cc += 4)
      s += zsum[(size_t)(bh * NCHUNK + cc) * 64 + i];
    zp4[qq][i] = s;
  }
  __syncthreads();  // B1: all LDS staged
  if (tid < 64) zpre[tid] = zp4[0][tid] + zp4[1][tid] + zp4[2][tid] + zp4[3][tid];

  // QK^T
  f32x4 sacc[4] = {};
#pragma unroll
  for (int ks = 0; ks < 2; ks++) {
    int ar = 16 * wvi + c;
    bf16x8 a = *(const bf16x8*)(Qs + ar * 64 + (((ks * 4 + quad) ^ (c & 7)) << 3));
#pragma unroll
    for (int j = 0; j < 4; j++) {
      int br = 16 * j + c;
      bf16x8 bb = *(const bf16x8*)(Ks + br * 64 + (((ks * 4 + quad) ^ (c & 7)) << 3));
      sacc[j] = __builtin_amdgcn_mfma_f32_16x16x32_bf16(a, bb, sacc[j], 0, 0, 0);
    }
  }

  // mask, rowsum, write Asm
  float rs[4] = {0.f, 0.f, 0.f, 0.f};
#pragma unroll
  for (int j = 0; j < 4; j++) {
#pragma unroll
    for (int r = 0; r < 4; r++) {
      int t = 16 * wvi + quad * 4 + r, s = 16 * j + c;
      float v = (s <= t) ? sacc[j][r] : 0.f;
      rs[r] += v;
      Asm[t * 64 + sw_t(t, s >> 3) + (s & 7)] = (bf16)v;
    }
  }
#pragma unroll
  for (int r = 0; r < 4; r++) {
    float v = rs[r];
    v += __shfl_xor(v, 1); v += __shfl_xor(v, 2);
    v += __shfl_xor(v, 4); v += __shfl_xor(v, 8);
    if (c == 0) rsum[16 * wvi + quad * 4 + r] = v;
  }
  __syncthreads();  // B2: Asm, rsum, zpre visible

  // den[t] = max(rowsum + Q[t].z_pre, 1e-6)
  if (tid < 64) {
    float s = rsum[tid];
    int t7 = tid & 7;
#pragma unroll
    for (int kg = 0; kg < 8; kg++) {
      bf16x8 qv = *(const bf16x8*)(Qs + tid * 64 + ((kg ^ t7) << 3));
#pragma unroll
      for (int u = 0; u < 8; u++) s += (float)qv[u] * zpre[kg * 8 + u];
    }
    den[tid] = fmaxf(s, 1e-6f);
  }

  // O = Q.S_pre + A.V
  f32x4 oacc[4] = {};
#pragma unroll
  for (int ks = 0; ks < 2; ks++) {
    int ar = 16 * wvi + c;
    bf16x8 aq = *(const bf16x8*)(Qs + ar * 64 + (((ks * 4 + quad) ^ (c & 7)) << 3));
    bf16x8 aa = *(const bf16x8*)(Asm + ar * 64 + sw_t(ar, ks * 4 + quad));
#pragma unroll
    for (int j = 0; j < 4; j++) {
      int br = 16 * j + c;
      bf16x8 bs = *(const bf16x8*)(Spre + br * 64 + sw_t(br, ks * 4 + quad));
      bf16x8 bv = *(const bf16x8*)(Vt + br * 64 + sw_t(br, ks * 4 + quad));
      oacc[j] = __builtin_amdgcn_mfma_f32_16x16x32_bf16(aq, bs, oacc[j], 0, 0, 0);
      oacc[j] = __builtin_amdgcn_mfma_f32_16x16x32_bf16(aa, bv, oacc[j], 0, 0, 0);
    }
  }
  __syncthreads();  // B3: den visible; Qs/Ks region dead -> repack scratch

  // O repack (stride 76) + vector store
  {
    bf16* shr = SH;   // 64*76 = 4864 elems, overlays Qs/Ks
#pragma unroll
    for (int r = 0; r < 4; r++) {
      int t = 16 * wvi + quad * 4 + r;
      float rd = 1.f / den[t];
#pragma unroll
      for (int j = 0; j < 4; j++)
        shr[t * 76 + 16 * j + c] = (bf16)(oacc[j][r] * rd);
    }
    __syncthreads();
    int row = tid >> 2, col0 = (tid & 3) * 16;
    bf16x8 v0 = *(const bf16x8*)(shr + row * 76 + col0);
    bf16x8 v1 = *(const bf16x8*)(shr + row * 76 + col0 + 8);
    bf16* od = O + (size_t)(rowbase + row) * 512 + h * 64 + col0;
    *(bf16x8*)od = v0;
    *(bf16x8*)(od + 8) = v1;
  }
}

extern "C" void kernel_launch(void* const* d_in, const int* in_sizes, int n_in,
                              void* d_out, int out_size, void* d_ws, size_t ws_size,
                              hipStream_t stream) {
  const float* x  = (const float*)d_in[0];
  const float* wq = (const float*)d_in[1];
  const float* wk = (const float*)d_in[2];
  const float* wv = (const float*)d_in[3];
  const float* wo = (const float*)d_in[4];
  float* out = (float*)d_out;

  char* p = (char*)d_ws;
  bf16* x_bf   = (bf16*)p; p += (size_t)MROWS * DMODEL * 2;
  bf16* wqkv_b = (bf16*)p; p += (size_t)3 * DMODEL * DMODEL * 2;
  bf16* wo_b   = (bf16*)p; p += (size_t)DMODEL * DMODEL * 2;
  bf16* Qb     = (bf16*)p; p += (size_t)MROWS * 512 * 2;
  bf16* Kb     = (bf16*)p; p += (size_t)MROWS * 512 * 2;
  bf16* Vb     = (bf16*)p; p += (size_t)MROWS * 512 * 2;
  bf16* Ob     = (bf16*)p; p += (size_t)MROWS * 512 * 2;
  bf16* KVs    = (bf16*)p; p += (size_t)BH * NCHUNK * DHEAD * DVAL * 2;
  float* zs    = (float*)p; p += (size_t)BH * NCHUNK * DHEAD * 4;

  k_convert<<<2048, 256, 0, stream>>>(x, wq, wk, wv, wo, x_bf, wqkv_b, wo_b);
  k_gemm_qkv<<<dim3(MROWS / 64, (3 * DMODEL) / 128), 256, 0, stream>>>(
      x_bf, wqkv_b, Qb, Kb, Vb);
  k_state<<<dim3(NCHUNK, BH), 256, 0, stream>>>(Kb, Vb, KVs, zs);
  k_attn<<<dim3(NCHUNK, BH), 256, 0, stream>>>(Qb, Kb, Vb, KVs, zs, Ob);
  k_gemm_out<<<dim3(MROWS / 64, DMODEL / 64), 256, 0, stream>>>(Ob, wo_b, out);
}